// Round 3
// 292.543 us; speedup vs baseline: 1.0189x; 1.0189x over previous
//
#include <hip/hip_runtime.h>

#define CDIM 64
#define NDIM 4096
#define BATCH 4
#define TILE 128
#define ROWP 72   // padded LDS row length in shorts (64 bf16 + 8 pad = 144 B)

typedef __attribute__((ext_vector_type(8))) short          bf16x8;
typedef __attribute__((ext_vector_type(4))) float          f32x4;
typedef __attribute__((ext_vector_type(4))) unsigned short ush4;

__device__ __forceinline__ unsigned short f2bf(float x) {
    unsigned int u = __builtin_bit_cast(unsigned int, x);
    u += 0x7fffu + ((u >> 16) & 1u);          // round-to-nearest-even
    return (unsigned short)(u >> 16);
}

__device__ __forceinline__ float bf2f(unsigned short s) {
    unsigned int u = ((unsigned int)s) << 16;
    return __builtin_bit_cast(float, u);
}

// ---------------------------------------------------------------------------
// Single kernel, no workspace, single launch (Round-0 verified structure).
// One change vs Round 0: MFMA operands are SWAPPED (acc = mfma(B_frag,
// A_frag)), which transposes the C/D fragment layout to col=lane&15 -> i,
// row=(lane>>4)*4+r -> j. Each lane then holds 4 CONSECUTIVE j values, so
// the epilogue is 16 packed global_store_dwordx4 per thread instead of 64
// scalar global_store_dword (4x fewer VMEM issues, less epilogue VALU).
// ---------------------------------------------------------------------------
__global__ __launch_bounds__(256)
void distmap_kernel(const float* __restrict__ A,
                    const float* __restrict__ B,
                    float* __restrict__ D) {
    __shared__ unsigned short At[TILE * ROWP];   // 18 KiB
    __shared__ unsigned short Bt[TILE * ROWP];   // 18 KiB
    __shared__ float aa_s[TILE];
    __shared__ float bb_s[TILE];

    const int t  = threadIdx.x;
    const int j0 = blockIdx.x * TILE;
    const int i0 = blockIdx.y * TILE;
    const int bz = blockIdx.z;

    const float* Ab = A + (size_t)bz * CDIM * NDIM;
    const float* Bb = B + (size_t)bz * CDIM * NDIM;

    // ---- stage both tiles: global [c][n] fp32 -> LDS [n][c] bf16 ----
    {
        const int f  = t & 31;   // n-block (n = 4f .. 4f+3)
        const int cb = t >> 5;   // c-block base (0..7)
        for (int s = 0; s < 2; ++s) {
            const int c = 4 * (cb + 8 * s);          // 0..60 step 4
            f32x4 ra[4], rb[4];
            for (int r = 0; r < 4; ++r) {
                ra[r] = *(const f32x4*)(Ab + (size_t)(c + r) * NDIM + i0 + 4 * f);
                rb[r] = *(const f32x4*)(Bb + (size_t)(c + r) * NDIM + j0 + 4 * f);
            }
            for (int q = 0; q < 4; ++q) {
                ush4 wa, wb;
                wa.x = f2bf(ra[0][q]); wa.y = f2bf(ra[1][q]);
                wa.z = f2bf(ra[2][q]); wa.w = f2bf(ra[3][q]);
                wb.x = f2bf(rb[0][q]); wb.y = f2bf(rb[1][q]);
                wb.z = f2bf(rb[2][q]); wb.w = f2bf(rb[3][q]);
                *(ush4*)&At[(4 * f + q) * ROWP + c] = wa;
                *(ush4*)&Bt[(4 * f + q) * ROWP + c] = wb;
            }
        }
    }
    __syncthreads();

    // ---- squared norms from the SAME bf16 values (consistent rounding) ----
    {
        const int r = t & 127;
        const unsigned short* src = (t < 128) ? &At[r * ROWP] : &Bt[r * ROWP];
        float s = 0.f;
        for (int k8 = 0; k8 < 8; ++k8) {
            bf16x8 v8 = *(const bf16x8*)(src + k8 * 8);
            for (int e = 0; e < 8; ++e) {
                float v = bf2f((unsigned short)v8[e]);
                s += v * v;
            }
        }
        if (t < 128) aa_s[r] = s; else bb_s[r] = s;
    }
    __syncthreads();

    // ---- MFMA (swapped operands): wave wv owns i-rows [wv*32, wv*32+32) ----
    const int wv   = t >> 6;
    const int lane = t & 63;
    const int lm   = lane & 15;
    const int lq   = lane >> 4;        // 0..3
    const int kb   = lq * 8;           // k-offset in shorts

    bf16x8 afr[2][2];
    #pragma unroll
    for (int m = 0; m < 2; ++m) {
        const int row = wv * 32 + m * 16 + lm;
        afr[m][0] = *(const bf16x8*)&At[row * ROWP + kb];
        afr[m][1] = *(const bf16x8*)&At[row * ROWP + 32 + kb];
    }

    f32x4 acc[2][8];
    #pragma unroll
    for (int m = 0; m < 2; ++m)
        #pragma unroll
        for (int n = 0; n < 8; ++n)
            acc[m][n] = (f32x4){0.f, 0.f, 0.f, 0.f};

    #pragma unroll
    for (int n = 0; n < 8; ++n) {
        const int row = n * 16 + lm;
        bf16x8 b0 = *(const bf16x8*)&Bt[row * ROWP + kb];
        bf16x8 b1 = *(const bf16x8*)&Bt[row * ROWP + 32 + kb];
        // swapped: B rows as the "A-matrix" operand, A rows as "B-matrix".
        acc[0][n] = __builtin_amdgcn_mfma_f32_16x16x32_bf16(b0, afr[0][0], acc[0][n], 0, 0, 0);
        acc[0][n] = __builtin_amdgcn_mfma_f32_16x16x32_bf16(b1, afr[0][1], acc[0][n], 0, 0, 0);
        acc[1][n] = __builtin_amdgcn_mfma_f32_16x16x32_bf16(b0, afr[1][0], acc[1][n], 0, 0, 0);
        acc[1][n] = __builtin_amdgcn_mfma_f32_16x16x32_bf16(b1, afr[1][1], acc[1][n], 0, 0, 0);
    }

    // ---- epilogue: d = aa[i] + bb[j] - 2*ab ----
    // Transposed C/D layout: i = i0 + wv*32 + m*16 + lm (col=lane&15),
    //                        j = j0 + n*16 + lq*4 + r   (row=(lane>>4)*4+r).
    float* Db = D + (size_t)bz * NDIM * NDIM;
    #pragma unroll
    for (int m = 0; m < 2; ++m) {
        const int il = wv * 32 + m * 16 + lm;
        const float aav = aa_s[il];
        float* rowp = Db + (size_t)(i0 + il) * NDIM + j0;
        #pragma unroll
        for (int n = 0; n < 8; ++n) {
            f32x4 bbq = *(const f32x4*)&bb_s[n * 16 + lq * 4];
            f32x4 d;
            #pragma unroll
            for (int r = 0; r < 4; ++r)
                d[r] = aav + bbq[r] - 2.0f * acc[m][n][r];
            *(f32x4*)(rowp + n * 16 + lq * 4) = d;
        }
    }
}

extern "C" void kernel_launch(void* const* d_in, const int* in_sizes, int n_in,
                              void* d_out, int out_size, void* d_ws, size_t ws_size,
                              hipStream_t stream) {
    const float* a = (const float*)d_in[0];
    const float* b = (const float*)d_in[1];
    float* out = (float*)d_out;
    const int batch = in_sizes[0] / (CDIM * NDIM);   // = 4
    dim3 grid(NDIM / TILE, NDIM / TILE, batch);
    distmap_kernel<<<grid, dim3(256), 0, stream>>>(a, b, out);
}

// Round 4
// 290.495 us; speedup vs baseline: 1.0261x; 1.0071x over previous
//
#include <hip/hip_runtime.h>

#define CDIM 64
#define NDIM 4096
#define BATCH 4
#define TILE 128
#define ROWP 72   // fallback kernel: padded LDS row length in shorts

typedef __attribute__((ext_vector_type(8))) short          bf16x8;
typedef __attribute__((ext_vector_type(4))) float          f32x4;
typedef __attribute__((ext_vector_type(8))) unsigned short ush8;
typedef __attribute__((ext_vector_type(4))) unsigned short ush4;

__device__ __forceinline__ unsigned short f2bf(float x) {
    unsigned int u = __builtin_bit_cast(unsigned int, x);
    u += 0x7fffu + ((u >> 16) & 1u);          // round-to-nearest-even
    return (unsigned short)(u >> 16);
}

__device__ __forceinline__ float bf2f(unsigned short s) {
    unsigned int u = ((unsigned int)s) << 16;
    return __builtin_bit_cast(float, u);
}

// ---------------------------------------------------------------------------
// Kernel 1 (prep, ~4 us): [bz][c][n] f32  ->  [bz][n][c] bf16 (transposed),
// plus squared norms computed from the SAME bf16-rounded values (numerics
// bit-identical to the Round-3 single kernel: same rounding, same sum order).
// blockIdx.y: 0 = A, 1 = B.  One thread per (bz, n) column.
// ---------------------------------------------------------------------------
__global__ __launch_bounds__(256)
void prep_kernel(const float* __restrict__ A, const float* __restrict__ B,
                 unsigned short* __restrict__ Tbf, float* __restrict__ nrm) {
    const int which = blockIdx.y;
    const float* src       = which ? B : A;
    unsigned short* dst    = Tbf + (size_t)which * BATCH * NDIM * CDIM;
    float* nd              = nrm + (size_t)which * BATCH * NDIM;

    const int gid = blockIdx.x * 256 + threadIdx.x;   // 0 .. BATCH*NDIM-1
    const int bz  = gid >> 12;                        // NDIM = 4096 = 2^12
    const int n   = gid & (NDIM - 1);
    const float* sb = src + (size_t)bz * CDIM * NDIM + n;

    ush8 w[8];                     // 64 bf16 = 128 B, statically indexed
    float s = 0.f;
    #pragma unroll
    for (int c = 0; c < CDIM; ++c) {
        float v = sb[(size_t)c * NDIM];    // coalesced across threads
        unsigned short h = f2bf(v);
        float rv = bf2f(h);
        s += rv * rv;                      // norm from ROUNDED value
        w[c >> 3][c & 7] = h;
    }
    unsigned short* o = dst + ((size_t)bz * NDIM + n) * CDIM;
    #pragma unroll
    for (int h = 0; h < 8; ++h)
        *(ush8*)(o + 8 * h) = w[h];        // 8 x 16B contiguous per row
    nd[(size_t)bz * NDIM + n] = s;
}

// ---------------------------------------------------------------------------
// Kernel 2 (main): pure register GEMM-epilogue streamer.
//  - No LDS, no __syncthreads: bf16 inputs are 4 MB total (L2-resident;
//    ~24 KB/block -> L1-resident), fragments load straight to VGPRs.
//  - SWAPPED mfma operands (verified +delta in Round 3): transposed C/D
//    layout, each lane holds 4 CONSECUTIVE j values => epilogue is 8 packed
//    global_store_dwordx4 per thread.
//  - Block tile 128(i) x 64(j); wave wv owns i-rows [wv*32, wv*32+32).
//    ~150 VALU insts/thread vs ~640 in the fused version.
// ---------------------------------------------------------------------------
__global__ __launch_bounds__(256)
void distmap_main(const unsigned short* __restrict__ Abf,
                  const unsigned short* __restrict__ Bbf,
                  const float* __restrict__ aa,
                  const float* __restrict__ bb,
                  float* __restrict__ D) {
    const int t    = threadIdx.x;
    const int wv   = t >> 6;
    const int lane = t & 63;
    const int lm   = lane & 15;
    const int lq   = lane >> 4;          // 0..3

    const int j0 = blockIdx.x * 64;
    const int i0 = blockIdx.y * 128 + wv * 32;
    const int bz = blockIdx.z;

    const unsigned short* Ab = Abf + (size_t)bz * NDIM * CDIM;
    const unsigned short* Bb = Bbf + (size_t)bz * NDIM * CDIM;

    bf16x8 afr[2][2];
    #pragma unroll
    for (int m = 0; m < 2; ++m) {
        const unsigned short* p = Ab + (size_t)(i0 + m * 16 + lm) * CDIM + lq * 8;
        afr[m][0] = *(const bf16x8*)(p);
        afr[m][1] = *(const bf16x8*)(p + 32);
    }

    f32x4 acc[2][4];
    #pragma unroll
    for (int m = 0; m < 2; ++m)
        #pragma unroll
        for (int n = 0; n < 4; ++n)
            acc[m][n] = (f32x4){0.f, 0.f, 0.f, 0.f};

    #pragma unroll
    for (int n = 0; n < 4; ++n) {
        const unsigned short* p = Bb + (size_t)(j0 + n * 16 + lm) * CDIM + lq * 8;
        bf16x8 b0 = *(const bf16x8*)(p);
        bf16x8 b1 = *(const bf16x8*)(p + 32);
        #pragma unroll
        for (int m = 0; m < 2; ++m) {
            acc[m][n] = __builtin_amdgcn_mfma_f32_16x16x32_bf16(b0, afr[m][0], acc[m][n], 0, 0, 0);
            acc[m][n] = __builtin_amdgcn_mfma_f32_16x16x32_bf16(b1, afr[m][1], acc[m][n], 0, 0, 0);
        }
    }

    const float* aaB = aa + (size_t)bz * NDIM;
    const float* bbB = bb + (size_t)bz * NDIM;
    float aav[2];
    #pragma unroll
    for (int m = 0; m < 2; ++m)
        aav[m] = aaB[i0 + m * 16 + lm];
    f32x4 bbq[4];
    #pragma unroll
    for (int n = 0; n < 4; ++n)
        bbq[n] = *(const f32x4*)(bbB + j0 + n * 16 + lq * 4);

    float* Dbase = D + (size_t)bz * NDIM * NDIM;
    #pragma unroll
    for (int m = 0; m < 2; ++m) {
        const size_t rowoff = (size_t)(i0 + m * 16 + lm) * NDIM;
        #pragma unroll
        for (int n = 0; n < 4; ++n) {
            f32x4 d;
            #pragma unroll
            for (int r = 0; r < 4; ++r)
                d[r] = aav[m] + bbq[n][r] - 2.0f * acc[m][n][r];
            *(f32x4*)(Dbase + rowoff + j0 + n * 16 + lq * 4) = d;
        }
    }
}

// ---------------------------------------------------------------------------
// Fallback: Round-3 harness-verified single kernel (no workspace needed).
// Swapped-operand MFMA + packed dwordx4 epilogue; 292.5 us measured.
// ---------------------------------------------------------------------------
__global__ __launch_bounds__(256)
void distmap_fallback(const float* __restrict__ A,
                      const float* __restrict__ B,
                      float* __restrict__ D) {
    __shared__ unsigned short At[TILE * ROWP];
    __shared__ unsigned short Bt[TILE * ROWP];
    __shared__ float aa_s[TILE];
    __shared__ float bb_s[TILE];

    const int t  = threadIdx.x;
    const int j0 = blockIdx.x * TILE;
    const int i0 = blockIdx.y * TILE;
    const int bz = blockIdx.z;

    const float* Ab = A + (size_t)bz * CDIM * NDIM;
    const float* Bb = B + (size_t)bz * CDIM * NDIM;

    {
        const int f  = t & 31;
        const int cb = t >> 5;
        for (int s = 0; s < 2; ++s) {
            const int c = 4 * (cb + 8 * s);
            f32x4 ra[4], rb[4];
            for (int r = 0; r < 4; ++r) {
                ra[r] = *(const f32x4*)(Ab + (size_t)(c + r) * NDIM + i0 + 4 * f);
                rb[r] = *(const f32x4*)(Bb + (size_t)(c + r) * NDIM + j0 + 4 * f);
            }
            for (int q = 0; q < 4; ++q) {
                ush4 wa, wb;
                wa.x = f2bf(ra[0][q]); wa.y = f2bf(ra[1][q]);
                wa.z = f2bf(ra[2][q]); wa.w = f2bf(ra[3][q]);
                wb.x = f2bf(rb[0][q]); wb.y = f2bf(rb[1][q]);
                wb.z = f2bf(rb[2][q]); wb.w = f2bf(rb[3][q]);
                *(ush4*)&At[(4 * f + q) * ROWP + c] = wa;
                *(ush4*)&Bt[(4 * f + q) * ROWP + c] = wb;
            }
        }
    }
    __syncthreads();

    {
        const int r = t & 127;
        const unsigned short* src = (t < 128) ? &At[r * ROWP] : &Bt[r * ROWP];
        float s = 0.f;
        for (int k8 = 0; k8 < 8; ++k8) {
            bf16x8 v8 = *(const bf16x8*)(src + k8 * 8);
            for (int e = 0; e < 8; ++e) {
                float v = bf2f((unsigned short)v8[e]);
                s += v * v;
            }
        }
        if (t < 128) aa_s[r] = s; else bb_s[r] = s;
    }
    __syncthreads();

    const int wv   = t >> 6;
    const int lane = t & 63;
    const int lm   = lane & 15;
    const int lq   = lane >> 4;
    const int kb   = lq * 8;

    bf16x8 afr[2][2];
    #pragma unroll
    for (int m = 0; m < 2; ++m) {
        const int row = wv * 32 + m * 16 + lm;
        afr[m][0] = *(const bf16x8*)&At[row * ROWP + kb];
        afr[m][1] = *(const bf16x8*)&At[row * ROWP + 32 + kb];
    }

    f32x4 acc[2][8];
    #pragma unroll
    for (int m = 0; m < 2; ++m)
        #pragma unroll
        for (int n = 0; n < 8; ++n)
            acc[m][n] = (f32x4){0.f, 0.f, 0.f, 0.f};

    #pragma unroll
    for (int n = 0; n < 8; ++n) {
        const int row = n * 16 + lm;
        bf16x8 b0 = *(const bf16x8*)&Bt[row * ROWP + kb];
        bf16x8 b1 = *(const bf16x8*)&Bt[row * ROWP + 32 + kb];
        acc[0][n] = __builtin_amdgcn_mfma_f32_16x16x32_bf16(b0, afr[0][0], acc[0][n], 0, 0, 0);
        acc[0][n] = __builtin_amdgcn_mfma_f32_16x16x32_bf16(b1, afr[0][1], acc[0][n], 0, 0, 0);
        acc[1][n] = __builtin_amdgcn_mfma_f32_16x16x32_bf16(b0, afr[1][0], acc[1][n], 0, 0, 0);
        acc[1][n] = __builtin_amdgcn_mfma_f32_16x16x32_bf16(b1, afr[1][1], acc[1][n], 0, 0, 0);
    }

    float* Db = D + (size_t)bz * NDIM * NDIM;
    #pragma unroll
    for (int m = 0; m < 2; ++m) {
        const int il = wv * 32 + m * 16 + lm;
        const float aav = aa_s[il];
        float* rowp = Db + (size_t)(i0 + il) * NDIM + j0;
        #pragma unroll
        for (int n = 0; n < 8; ++n) {
            f32x4 bbq = *(const f32x4*)&bb_s[n * 16 + lq * 4];
            f32x4 d;
            #pragma unroll
            for (int r = 0; r < 4; ++r)
                d[r] = aav + bbq[r] - 2.0f * acc[m][n][r];
            *(f32x4*)(rowp + n * 16 + lq * 4) = d;
        }
    }
}

extern "C" void kernel_launch(void* const* d_in, const int* in_sizes, int n_in,
                              void* d_out, int out_size, void* d_ws, size_t ws_size,
                              hipStream_t stream) {
    const float* a = (const float*)d_in[0];
    const float* b = (const float*)d_in[1];
    float* out = (float*)d_out;

    // Workspace layout: [A bf16 2MB][B bf16 2MB][aa 64KB][bb 64KB] = 4.33 MB.
    const size_t bf16_bytes = (size_t)2 * BATCH * NDIM * CDIM * sizeof(unsigned short);
    const size_t nrm_bytes  = (size_t)2 * BATCH * NDIM * sizeof(float);
    const size_t needed     = bf16_bytes + nrm_bytes;

    if (d_ws != nullptr && ws_size >= needed) {
        unsigned short* Tbf = (unsigned short*)d_ws;
        float* nrm = (float*)((char*)d_ws + bf16_bytes);

        prep_kernel<<<dim3(BATCH * NDIM / 256, 2), dim3(256), 0, stream>>>(a, b, Tbf, nrm);

        const unsigned short* Abf = Tbf;
        const unsigned short* Bbf = Tbf + (size_t)BATCH * NDIM * CDIM;
        const float* aa = nrm;
        const float* bb = nrm + (size_t)BATCH * NDIM;

        distmap_main<<<dim3(NDIM / 64, NDIM / 128, BATCH), dim3(256), 0, stream>>>(
            Abf, Bbf, aa, bb, out);
    } else {
        // Known-good single-kernel fallback (Round-3 verified, no workspace).
        dim3 grid(NDIM / TILE, NDIM / TILE, BATCH);
        distmap_fallback<<<grid, dim3(256), 0, stream>>>(a, b, out);
    }
}

// Round 5
// 288.515 us; speedup vs baseline: 1.0331x; 1.0069x over previous
//
#include <hip/hip_runtime.h>

#define CDIM 64
#define NDIM 4096
#define BATCH 4
#define TILE 128
#define ROWP 72   // fused kernels: padded LDS row length in shorts

// Scratch (in D tail): [Abf 2MiB][Bbf 2MiB][aa 64KiB][bb 64KiB]
#define ABF_BYTES   ((size_t)BATCH * NDIM * CDIM * 2)          // 2 MiB
#define NRM_BYTES   ((size_t)BATCH * NDIM * 4)                 // 64 KiB
#define SCRATCH_BYTES (2 * ABF_BYTES + 2 * NRM_BYTES)          // 4,325,376
#define TAIL_TROWS  3                                          // 128-row tiles
#define TAIL_I0     (NDIM - TAIL_TROWS * TILE)                 // 3712

typedef __attribute__((ext_vector_type(8))) short          bf16x8;
typedef __attribute__((ext_vector_type(4))) float          f32x4;
typedef __attribute__((ext_vector_type(8))) unsigned short ush8;
typedef __attribute__((ext_vector_type(4))) unsigned short ush4;

__device__ __forceinline__ unsigned short f2bf(float x) {
    unsigned int u = __builtin_bit_cast(unsigned int, x);
    u += 0x7fffu + ((u >> 16) & 1u);          // round-to-nearest-even
    return (unsigned short)(u >> 16);
}

__device__ __forceinline__ float bf2f(unsigned short s) {
    unsigned int u = ((unsigned int)s) << 16;
    return __builtin_bit_cast(float, u);
}

// ---------------------------------------------------------------------------
// Kernel 1 (prep): [bz][c][n] f32 -> [bz][n][c] bf16 (transposed) + norms
// from the SAME bf16-rounded values, summed c=0..63 (bit-identical order to
// the verified fused kernel). One thread per (bz, n). blockIdx.y: 0=A, 1=B.
// ---------------------------------------------------------------------------
__global__ __launch_bounds__(256)
void prep_kernel(const float* __restrict__ A, const float* __restrict__ B,
                 unsigned short* __restrict__ Tbf, float* __restrict__ nrm) {
    const int which = blockIdx.y;
    const float* src       = which ? B : A;
    unsigned short* dst    = Tbf + (size_t)which * BATCH * NDIM * CDIM;
    float* nd              = nrm + (size_t)which * BATCH * NDIM;

    const int gid = blockIdx.x * 256 + threadIdx.x;   // 0 .. BATCH*NDIM-1
    const int bz  = gid >> 12;                        // NDIM = 4096 = 2^12
    const int n   = gid & (NDIM - 1);
    const float* sb = src + (size_t)bz * CDIM * NDIM + n;

    ush8 w[8];
    float s = 0.f;
    #pragma unroll
    for (int c = 0; c < CDIM; ++c) {
        float v = sb[(size_t)c * NDIM];    // coalesced across threads
        unsigned short h = f2bf(v);
        float rv = bf2f(h);
        s += rv * rv;
        w[c >> 3][c & 7] = h;
    }
    unsigned short* o = dst + ((size_t)bz * NDIM + n) * CDIM;
    #pragma unroll
    for (int h = 0; h < 8; ++h)
        *(ush8*)(o + 8 * h) = w[h];
    nd[(size_t)bz * NDIM + n] = s;
}

// ---------------------------------------------------------------------------
// Kernel 2 (main): register-only streamer. No LDS, no barriers; fragments
// load straight from the 4 MB L2-resident bf16 buffer. Swapped MFMA operands
// (R3-verified): each lane holds 4 consecutive j => 8 packed dwordx4 stores.
// Block tile 128(i) x 64(j); wave wv owns i-rows [wv*32, wv*32+32).
// SKIPS the 3 tile-rows of batch 3 that hold the scratch (tail kernel fixes).
// ---------------------------------------------------------------------------
__global__ __launch_bounds__(256)
void distmap_main(const unsigned short* __restrict__ Abf,
                  const unsigned short* __restrict__ Bbf,
                  const float* __restrict__ aa,
                  const float* __restrict__ bb,
                  float* __restrict__ D) {
    const int bz = blockIdx.z;
    if (bz == BATCH - 1 && blockIdx.y >= (NDIM / 128 - TAIL_TROWS))
        return;   // scratch-resident rows: recomputed by tail kernel

    const int t    = threadIdx.x;
    const int wv   = t >> 6;
    const int lane = t & 63;
    const int lm   = lane & 15;
    const int lq   = lane >> 4;          // 0..3

    const int j0 = blockIdx.x * 64;
    const int i0 = blockIdx.y * 128 + wv * 32;

    const unsigned short* Ab = Abf + (size_t)bz * NDIM * CDIM;
    const unsigned short* Bb = Bbf + (size_t)bz * NDIM * CDIM;

    bf16x8 afr[2][2];
    #pragma unroll
    for (int m = 0; m < 2; ++m) {
        const unsigned short* p = Ab + (size_t)(i0 + m * 16 + lm) * CDIM + lq * 8;
        afr[m][0] = *(const bf16x8*)(p);
        afr[m][1] = *(const bf16x8*)(p + 32);
    }

    f32x4 acc[2][4];
    #pragma unroll
    for (int m = 0; m < 2; ++m)
        #pragma unroll
        for (int n = 0; n < 4; ++n)
            acc[m][n] = (f32x4){0.f, 0.f, 0.f, 0.f};

    #pragma unroll
    for (int n = 0; n < 4; ++n) {
        const unsigned short* p = Bb + (size_t)(j0 + n * 16 + lm) * CDIM + lq * 8;
        bf16x8 b0 = *(const bf16x8*)(p);
        bf16x8 b1 = *(const bf16x8*)(p + 32);
        #pragma unroll
        for (int m = 0; m < 2; ++m) {
            acc[m][n] = __builtin_amdgcn_mfma_f32_16x16x32_bf16(b0, afr[m][0], acc[m][n], 0, 0, 0);
            acc[m][n] = __builtin_amdgcn_mfma_f32_16x16x32_bf16(b1, afr[m][1], acc[m][n], 0, 0, 0);
        }
    }

    const float* aaB = aa + (size_t)bz * NDIM;
    const float* bbB = bb + (size_t)bz * NDIM;
    float aav[2];
    #pragma unroll
    for (int m = 0; m < 2; ++m)
        aav[m] = aaB[i0 + m * 16 + lm];
    f32x4 bbq[4];
    #pragma unroll
    for (int n = 0; n < 4; ++n)
        bbq[n] = *(const f32x4*)(bbB + j0 + n * 16 + lq * 4);

    float* Dbase = D + (size_t)bz * NDIM * NDIM;
    #pragma unroll
    for (int m = 0; m < 2; ++m) {
        const size_t rowoff = (size_t)(i0 + m * 16 + lm) * NDIM;
        #pragma unroll
        for (int n = 0; n < 4; ++n) {
            f32x4 d;
            #pragma unroll
            for (int r = 0; r < 4; ++r)
                d[r] = aav[m] + bbq[n][r] - 2.0f * acc[m][n][r];
            *(f32x4*)(Dbase + rowoff + j0 + n * 16 + lq * 4) = d;
        }
    }
}

// ---------------------------------------------------------------------------
// Fused kernel (verbatim Round-3, harness-verified 292.5us full-grid).
// Used as: (a) tail cleanup over the scratch region (i0base=TAIL_I0, bz
// fixed to BATCH-1 via gridDim.z==1 + zoff), (b) full-grid safety fallback.
// Reads ORIGINAL f32 inputs, so it is independent of the scratch.
// ---------------------------------------------------------------------------
__global__ __launch_bounds__(256)
void distmap_fused(const float* __restrict__ A,
                   const float* __restrict__ B,
                   float* __restrict__ D,
                   int i0base, int zoff) {
    __shared__ unsigned short At[TILE * ROWP];
    __shared__ unsigned short Bt[TILE * ROWP];
    __shared__ float aa_s[TILE];
    __shared__ float bb_s[TILE];

    const int t  = threadIdx.x;
    const int j0 = blockIdx.x * TILE;
    const int i0 = i0base + blockIdx.y * TILE;
    const int bz = blockIdx.z + zoff;

    const float* Ab = A + (size_t)bz * CDIM * NDIM;
    const float* Bb = B + (size_t)bz * CDIM * NDIM;

    {
        const int f  = t & 31;
        const int cb = t >> 5;
        for (int s = 0; s < 2; ++s) {
            const int c = 4 * (cb + 8 * s);
            f32x4 ra[4], rb[4];
            for (int r = 0; r < 4; ++r) {
                ra[r] = *(const f32x4*)(Ab + (size_t)(c + r) * NDIM + i0 + 4 * f);
                rb[r] = *(const f32x4*)(Bb + (size_t)(c + r) * NDIM + j0 + 4 * f);
            }
            for (int q = 0; q < 4; ++q) {
                ush4 wa, wb;
                wa.x = f2bf(ra[0][q]); wa.y = f2bf(ra[1][q]);
                wa.z = f2bf(ra[2][q]); wa.w = f2bf(ra[3][q]);
                wb.x = f2bf(rb[0][q]); wb.y = f2bf(rb[1][q]);
                wb.z = f2bf(rb[2][q]); wb.w = f2bf(rb[3][q]);
                *(ush4*)&At[(4 * f + q) * ROWP + c] = wa;
                *(ush4*)&Bt[(4 * f + q) * ROWP + c] = wb;
            }
        }
    }
    __syncthreads();

    {
        const int r = t & 127;
        const unsigned short* src = (t < 128) ? &At[r * ROWP] : &Bt[r * ROWP];
        float s = 0.f;
        for (int k8 = 0; k8 < 8; ++k8) {
            bf16x8 v8 = *(const bf16x8*)(src + k8 * 8);
            for (int e = 0; e < 8; ++e) {
                float v = bf2f((unsigned short)v8[e]);
                s += v * v;
            }
        }
        if (t < 128) aa_s[r] = s; else bb_s[r] = s;
    }
    __syncthreads();

    const int wv   = t >> 6;
    const int lane = t & 63;
    const int lm   = lane & 15;
    const int lq   = lane >> 4;
    const int kb   = lq * 8;

    bf16x8 afr[2][2];
    #pragma unroll
    for (int m = 0; m < 2; ++m) {
        const int row = wv * 32 + m * 16 + lm;
        afr[m][0] = *(const bf16x8*)&At[row * ROWP + kb];
        afr[m][1] = *(const bf16x8*)&At[row * ROWP + 32 + kb];
    }

    f32x4 acc[2][8];
    #pragma unroll
    for (int m = 0; m < 2; ++m)
        #pragma unroll
        for (int n = 0; n < 8; ++n)
            acc[m][n] = (f32x4){0.f, 0.f, 0.f, 0.f};

    #pragma unroll
    for (int n = 0; n < 8; ++n) {
        const int row = n * 16 + lm;
        bf16x8 b0 = *(const bf16x8*)&Bt[row * ROWP + kb];
        bf16x8 b1 = *(const bf16x8*)&Bt[row * ROWP + 32 + kb];
        acc[0][n] = __builtin_amdgcn_mfma_f32_16x16x32_bf16(b0, afr[0][0], acc[0][n], 0, 0, 0);
        acc[0][n] = __builtin_amdgcn_mfma_f32_16x16x32_bf16(b1, afr[0][1], acc[0][n], 0, 0, 0);
        acc[1][n] = __builtin_amdgcn_mfma_f32_16x16x32_bf16(b0, afr[1][0], acc[1][n], 0, 0, 0);
        acc[1][n] = __builtin_amdgcn_mfma_f32_16x16x32_bf16(b1, afr[1][1], acc[1][n], 0, 0, 0);
    }

    float* Db = D + (size_t)bz * NDIM * NDIM;
    #pragma unroll
    for (int m = 0; m < 2; ++m) {
        const int il = wv * 32 + m * 16 + lm;
        const float aav = aa_s[il];
        float* rowp = Db + (size_t)(i0 + il) * NDIM + j0;
        #pragma unroll
        for (int n = 0; n < 8; ++n) {
            f32x4 bbq = *(const f32x4*)&bb_s[n * 16 + lq * 4];
            f32x4 d;
            #pragma unroll
            for (int r = 0; r < 4; ++r)
                d[r] = aav + bbq[r] - 2.0f * acc[m][n][r];
            *(f32x4*)(rowp + n * 16 + lq * 4) = d;
        }
    }
}

extern "C" void kernel_launch(void* const* d_in, const int* in_sizes, int n_in,
                              void* d_out, int out_size, void* d_ws, size_t ws_size,
                              hipStream_t stream) {
    const float* a = (const float*)d_in[0];
    const float* b = (const float*)d_in[1];
    float* out = (float*)d_out;

    const size_t expect = (size_t)BATCH * NDIM * NDIM * sizeof(float);

    if ((size_t)out_size == expect) {
        // Scratch lives in the last 264 rows of batch 3 of D (tile-aligned
        // skip region = last 384 rows, recomputed by the tail launch).
        char* scr = (char*)d_out + expect - SCRATCH_BYTES;
        unsigned short* Abf = (unsigned short*)scr;
        unsigned short* Bbf = (unsigned short*)(scr + ABF_BYTES);
        float* aa = (float*)(scr + 2 * ABF_BYTES);
        float* bb = (float*)(scr + 2 * ABF_BYTES + NRM_BYTES);

        // 1) convert+transpose+norms into scratch
        prep_kernel<<<dim3(BATCH * NDIM / 256, 2), dim3(256), 0, stream>>>(
            a, b, (unsigned short*)scr, aa);
        // 2) streamer over everything except the scratch tile-rows
        distmap_main<<<dim3(NDIM / 64, NDIM / 128, BATCH), dim3(256), 0, stream>>>(
            Abf, Bbf, aa, bb, out);
        // 3) recompute scratch tile-rows from original f32 inputs
        distmap_fused<<<dim3(NDIM / TILE, TAIL_TROWS, 1), dim3(256), 0, stream>>>(
            a, b, out, TAIL_I0, BATCH - 1);
    } else {
        // Safety fallback: full-grid fused kernel (R3-verified).
        distmap_fused<<<dim3(NDIM / TILE, NDIM / TILE, BATCH), dim3(256), 0, stream>>>(
            a, b, out, 0, 0);
    }
}